// Round 2
// baseline (1970.215 us; speedup 1.0000x reference)
//
#include <hip/hip_runtime.h>
#include <hip/hip_bf16.h>
#include <math.h>

// MoE top-2/8, T=4096, d=1024, ffn=3584. fp32 in/out, bf16 MFMA internally.
// R2: same routed grouped-GEMM as R1 + ws_size guard (suspected container
// crash from ws overflow if ws_size < ~63.2 MiB; guard makes that a clean
// numeric failure instead of a GPU fault).

#define NUM_EXPERTS 8
#define TOPK 2
#define D_MODEL 1024
#define D_MLP 3584
#define T_TOKENS 4096
#define NSLOT (T_TOKENS * TOPK)
#define SLOT_CAP 9216  // 8192 + 8*128 worst-case padding

#define BM 128
#define BN 128
#define BK 32
#define LDT 40  // LDS row pitch in bf16 elems (32 + 8 pad; 2-way bank alias = free)

typedef __attribute__((ext_vector_type(8))) short bf16x8;
typedef __attribute__((ext_vector_type(4))) float f32x4;

#define WS_H_OFFSET 147456
#define WS_NEEDED (WS_H_OFFSET + (size_t)SLOT_CAP * D_MLP * 2)

__device__ inline unsigned short f32_to_bf16(float f) {
  union { float f; unsigned int u; } v; v.f = f;
  unsigned int u = v.u;
  unsigned int r = (u + 0x7FFFu + ((u >> 16) & 1u)) >> 16;  // RNE
  return (unsigned short)r;
}

__device__ inline bf16x8 pack8(float4 a, float4 b) {
  bf16x8 v;
  v[0] = (short)f32_to_bf16(a.x); v[1] = (short)f32_to_bf16(a.y);
  v[2] = (short)f32_to_bf16(a.z); v[3] = (short)f32_to_bf16(a.w);
  v[4] = (short)f32_to_bf16(b.x); v[5] = (short)f32_to_bf16(b.y);
  v[6] = (short)f32_to_bf16(b.z); v[7] = (short)f32_to_bf16(b.w);
  return v;
}

// ---------------- zero d_out ----------------
__global__ void zero_kernel(float4* __restrict__ p, int n4) {
  int i = blockIdx.x * blockDim.x + threadIdx.x;
  if (i < n4) p[i] = make_float4(0.f, 0.f, 0.f, 0.f);
}

// ---------------- gating: one wave per token ----------------
__global__ void gate_kernel(const float* __restrict__ x,
                            const float* __restrict__ Wg,
                            int* __restrict__ top_idx,
                            float* __restrict__ top_w) {
  const int t = blockIdx.x;
  const int lane = threadIdx.x;  // 64 threads
  const float* xr = x + (size_t)t * D_MODEL;

  float xs[16];
#pragma unroll
  for (int i = 0; i < 16; ++i) xs[i] = xr[lane + i * 64];

  float logits[NUM_EXPERTS];
#pragma unroll
  for (int e = 0; e < NUM_EXPERTS; ++e) {
    const float* wr = Wg + (size_t)e * D_MODEL;
    float s = 0.f;
#pragma unroll
    for (int i = 0; i < 16; ++i) s += xs[i] * wr[lane + i * 64];
    for (int o = 32; o > 0; o >>= 1) s += __shfl_down(s, o);
    logits[e] = s;  // valid on lane 0
  }

  if (lane == 0) {
    int i0 = 0;
#pragma unroll
    for (int e = 1; e < NUM_EXPERTS; ++e)
      if (logits[e] > logits[i0]) i0 = e;
    int i1 = -1;
#pragma unroll
    for (int e = 0; e < NUM_EXPERTS; ++e) {
      if (e == i0) continue;
      if (i1 < 0 || logits[e] > logits[i1]) i1 = e;
    }
    // softmax over 8 then renorm top-2 == 2-way softmax over the top-2 logits
    float w0 = 1.0f / (1.0f + expf(logits[i1] - logits[i0]));
    top_idx[2 * t] = i0; top_idx[2 * t + 1] = i1;
    top_w[2 * t] = w0;   top_w[2 * t + 1] = 1.0f - w0;
  }
}

// ---------------- routing: single block ----------------
__global__ void route_kernel(const int* __restrict__ top_idx,
                             const float* __restrict__ top_w,
                             int* __restrict__ hdr,
                             int* __restrict__ slot_token,
                             float* __restrict__ slot_weight) {
  __shared__ int cnt[NUM_EXPERTS];
  __shared__ int off[NUM_EXPERTS];
  __shared__ int cur[NUM_EXPERTS];
  const int tid = threadIdx.x;  // 256
  if (tid < NUM_EXPERTS) cnt[tid] = 0;
  __syncthreads();
  for (int k = tid; k < NSLOT; k += 256) atomicAdd(&cnt[top_idx[k]], 1);
  __syncthreads();
  if (tid == 0) {
    int o = 0;
    for (int e = 0; e < NUM_EXPERTS; ++e) {
      off[e] = o;
      int p = (cnt[e] + BM - 1) & ~(BM - 1);
      hdr[e] = cnt[e];      // raw count
      hdr[8 + e] = o;       // base slot offset (128-aligned)
      hdr[16 + e] = p;      // padded count
      o += p;
    }
  }
  __syncthreads();
  if (tid < NUM_EXPERTS) cur[tid] = off[tid];
  for (int i = tid; i < SLOT_CAP; i += 256) { slot_token[i] = 0; slot_weight[i] = 0.0f; }
  __syncthreads();
  for (int k = tid; k < NSLOT; k += 256) {
    int e = top_idx[k];
    int p = atomicAdd(&cur[e], 1);
    slot_token[p] = k >> 1;
    slot_weight[p] = top_w[k];
  }
}

// ---------------- GEMM1: H = silu(Xg W1^T) * (Xg W3^T), bf16 out ----------------
__global__ void gemm1_kernel(const float* __restrict__ x,
                             const float* __restrict__ W1,
                             const float* __restrict__ W3,
                             const int* __restrict__ hdr,
                             const int* __restrict__ slot_token,
                             unsigned short* __restrict__ H) {
  const int e = blockIdx.z;
  const int pad_cnt = hdr[16 + e];
  const int m0 = blockIdx.y * BM;
  if (m0 >= pad_cnt) return;
  const int base = hdr[8 + e];
  const int n0 = blockIdx.x * BN;

  __shared__ unsigned short As[BM * LDT];
  __shared__ unsigned short B1s[BN * LDT];
  __shared__ unsigned short B3s[BN * LDT];

  const int tid = threadIdx.x;
  const int lane = tid & 63;
  const int wave = tid >> 6;
  const int wm = (wave >> 1) * 64;
  const int wn = (wave & 1) * 64;
  const int l15 = lane & 15;
  const int quad = lane >> 4;

  // staging: thread -> (row = tid/2, 16 cols at (tid&1)*16)
  const int sr = tid >> 1;
  const int sc = (tid & 1) * 16;
  const float* arow = x + (size_t)slot_token[base + m0 + sr] * D_MODEL + sc;
  const float* b1row = W1 + ((size_t)e * D_MLP + n0 + sr) * D_MODEL + sc;
  const float* b3row = W3 + ((size_t)e * D_MLP + n0 + sr) * D_MODEL + sc;

  const f32x4 fzero = {0.f, 0.f, 0.f, 0.f};
  f32x4 acc1[4][4], acc3[4][4];
#pragma unroll
  for (int i = 0; i < 4; ++i)
#pragma unroll
    for (int j = 0; j < 4; ++j) { acc1[i][j] = fzero; acc3[i][j] = fzero; }

  for (int k0 = 0; k0 < D_MODEL; k0 += BK) {
    const float4* ap = (const float4*)(arow + k0);
    const float4* b1p = (const float4*)(b1row + k0);
    const float4* b3p = (const float4*)(b3row + k0);
    float4 a0 = ap[0], a1 = ap[1], a2 = ap[2], a3 = ap[3];
    float4 c0 = b1p[0], c1 = b1p[1], c2 = b1p[2], c3 = b1p[3];
    float4 d0 = b3p[0], d1 = b3p[1], d2 = b3p[2], d3 = b3p[3];
    __syncthreads();
    *(bf16x8*)(&As[sr * LDT + sc]) = pack8(a0, a1);
    *(bf16x8*)(&As[sr * LDT + sc + 8]) = pack8(a2, a3);
    *(bf16x8*)(&B1s[sr * LDT + sc]) = pack8(c0, c1);
    *(bf16x8*)(&B1s[sr * LDT + sc + 8]) = pack8(c2, c3);
    *(bf16x8*)(&B3s[sr * LDT + sc]) = pack8(d0, d1);
    *(bf16x8*)(&B3s[sr * LDT + sc + 8]) = pack8(d2, d3);
    __syncthreads();

    bf16x8 a_frag[4], b1_frag[4], b3_frag[4];
#pragma unroll
    for (int i = 0; i < 4; ++i)
      a_frag[i] = *(const bf16x8*)(&As[(wm + i * 16 + l15) * LDT + quad * 8]);
#pragma unroll
    for (int j = 0; j < 4; ++j) {
      b1_frag[j] = *(const bf16x8*)(&B1s[(wn + j * 16 + l15) * LDT + quad * 8]);
      b3_frag[j] = *(const bf16x8*)(&B3s[(wn + j * 16 + l15) * LDT + quad * 8]);
    }
#pragma unroll
    for (int i = 0; i < 4; ++i)
#pragma unroll
      for (int j = 0; j < 4; ++j) {
        acc1[i][j] = __builtin_amdgcn_mfma_f32_16x16x32_bf16(a_frag[i], b1_frag[j], acc1[i][j], 0, 0, 0);
        acc3[i][j] = __builtin_amdgcn_mfma_f32_16x16x32_bf16(a_frag[i], b3_frag[j], acc3[i][j], 0, 0, 0);
      }
  }

  // epilogue: silu(h1)*h3 -> bf16 H.  D layout: col=lane&15, row=quad*4+reg
  const size_t hbase = (size_t)(base + m0);
#pragma unroll
  for (int i = 0; i < 4; ++i) {
    const int mrow = wm + i * 16 + quad * 4;
#pragma unroll
    for (int r = 0; r < 4; ++r) {
      unsigned short* hrow = H + (hbase + mrow + r) * D_MLP + n0;
#pragma unroll
      for (int j = 0; j < 4; ++j) {
        float h1 = acc1[i][j][r];
        float h3 = acc3[i][j][r];
        float s = h1 / (1.0f + __expf(-h1));
        hrow[wn + j * 16 + l15] = f32_to_bf16(s * h3);
      }
    }
  }
}

// ---------------- GEMM2: out += gate_w * (H W2^T) ----------------
__global__ void gemm2_kernel(const unsigned short* __restrict__ H,
                             const float* __restrict__ W2,
                             const int* __restrict__ hdr,
                             const int* __restrict__ slot_token,
                             const float* __restrict__ slot_weight,
                             float* __restrict__ out) {
  const int e = blockIdx.z;
  const int pad_cnt = hdr[16 + e];
  const int m0 = blockIdx.y * BM;
  if (m0 >= pad_cnt) return;
  const int base = hdr[8 + e];
  const int n0 = blockIdx.x * BN;

  __shared__ unsigned short As[BM * LDT];
  __shared__ unsigned short Bs[BN * LDT];

  const int tid = threadIdx.x;
  const int lane = tid & 63;
  const int wave = tid >> 6;
  const int wm = (wave >> 1) * 64;
  const int wn = (wave & 1) * 64;
  const int l15 = lane & 15;
  const int quad = lane >> 4;

  const int sr = tid >> 1;
  const int sc = (tid & 1) * 16;
  const unsigned short* arow = H + (size_t)(base + m0 + sr) * D_MLP + sc;
  const float* brow = W2 + ((size_t)e * D_MODEL + n0 + sr) * D_MLP + sc;

  const f32x4 fzero = {0.f, 0.f, 0.f, 0.f};
  f32x4 acc[4][4];
#pragma unroll
  for (int i = 0; i < 4; ++i)
#pragma unroll
    for (int j = 0; j < 4; ++j) acc[i][j] = fzero;

  for (int k0 = 0; k0 < D_MLP; k0 += BK) {
    const uint4* ap = (const uint4*)(arow + k0);  // 8 bf16 per uint4
    uint4 a0 = ap[0], a1 = ap[1];
    const float4* bp = (const float4*)(brow + k0);
    float4 c0 = bp[0], c1 = bp[1], c2 = bp[2], c3 = bp[3];
    __syncthreads();
    *(uint4*)(&As[sr * LDT + sc]) = a0;
    *(uint4*)(&As[sr * LDT + sc + 8]) = a1;
    *(bf16x8*)(&Bs[sr * LDT + sc]) = pack8(c0, c1);
    *(bf16x8*)(&Bs[sr * LDT + sc + 8]) = pack8(c2, c3);
    __syncthreads();

    bf16x8 a_frag[4], b_frag[4];
#pragma unroll
    for (int i = 0; i < 4; ++i)
      a_frag[i] = *(const bf16x8*)(&As[(wm + i * 16 + l15) * LDT + quad * 8]);
#pragma unroll
    for (int j = 0; j < 4; ++j)
      b_frag[j] = *(const bf16x8*)(&Bs[(wn + j * 16 + l15) * LDT + quad * 8]);
#pragma unroll
    for (int i = 0; i < 4; ++i)
#pragma unroll
      for (int j = 0; j < 4; ++j)
        acc[i][j] = __builtin_amdgcn_mfma_f32_16x16x32_bf16(a_frag[i], b_frag[j], acc[i][j], 0, 0, 0);
  }

#pragma unroll
  for (int i = 0; i < 4; ++i) {
    const int mrow = wm + i * 16 + quad * 4;
#pragma unroll
    for (int r = 0; r < 4; ++r) {
      const int srow = base + m0 + mrow + r;
      const float w = slot_weight[srow];
      if (w != 0.0f) {
        const int tok = slot_token[srow];
        float* orow = out + (size_t)tok * D_MODEL + n0;
#pragma unroll
        for (int j = 0; j < 4; ++j)
          atomicAdd(&orow[wn + j * 16 + l15], acc[i][j][r] * w);
      }
    }
  }
}

extern "C" void kernel_launch(void* const* d_in, const int* in_sizes, int n_in,
                              void* d_out, int out_size, void* d_ws, size_t ws_size,
                              hipStream_t stream) {
  const float* x  = (const float*)d_in[0];
  const float* Wg = (const float*)d_in[1];
  const float* W1 = (const float*)d_in[2];
  const float* W3 = (const float*)d_in[3];
  const float* W2 = (const float*)d_in[4];
  float* out = (float*)d_out;

  // ws guard: if scratch is too small, do nothing (clean absmax failure
  // instead of an OOB write that kills the container).
  if (ws_size < WS_NEEDED) return;

  char* ws = (char*)d_ws;
  int*   top_idx     = (int*)(ws);                 // 8192 ints
  float* top_w       = (float*)(ws + 32768);       // 8192 floats
  int*   hdr         = (int*)(ws + 65536);         // 64 ints
  int*   slot_token  = (int*)(ws + 65792);         // 9216 ints
  float* slot_weight = (float*)(ws + 102656);      // 9216 floats
  unsigned short* H  = (unsigned short*)(ws + WS_H_OFFSET);  // 9216*3584 bf16 = 63 MiB

  zero_kernel<<<(out_size / 4 + 255) / 256, 256, 0, stream>>>((float4*)d_out, out_size / 4);
  gate_kernel<<<T_TOKENS, 64, 0, stream>>>(x, Wg, top_idx, top_w);
  route_kernel<<<1, 256, 0, stream>>>(top_idx, top_w, hdr, slot_token, slot_weight);
  gemm1_kernel<<<dim3(D_MLP / BN, T_TOKENS / BM, NUM_EXPERTS), 256, 0, stream>>>(
      x, W1, W3, hdr, slot_token, H);
  gemm2_kernel<<<dim3(D_MODEL / BN, T_TOKENS / BM, NUM_EXPERTS), 256, 0, stream>>>(
      H, W2, hdr, slot_token, slot_weight, out);
}

// Round 3
// 925.517 us; speedup vs baseline: 2.1288x; 2.1288x over previous
//
#include <hip/hip_runtime.h>
#include <hip/hip_bf16.h>
#include <math.h>

// MoE top-2/8, T=4096, d=1024, ffn=3584. fp32 in/out, bf16 MFMA internally.
// R3: add __launch_bounds__(256) to GEMM kernels. R2's default 1024-thread
// bound capped unified regs at 128/wave -> accumulator spill to scratch
// (VGPR_Count=64, WRITE_SIZE 3.8GB vs 66MB ideal, MfmaUtil 3.4%).

#define NUM_EXPERTS 8
#define TOPK 2
#define D_MODEL 1024
#define D_MLP 3584
#define T_TOKENS 4096
#define NSLOT (T_TOKENS * TOPK)
#define SLOT_CAP 9216  // 8192 + 8*128 worst-case padding

#define BM 128
#define BN 128
#define BK 32
#define LDT 40  // LDS row pitch in bf16 elems (32 + 8 pad; 2-way bank alias = free)

typedef __attribute__((ext_vector_type(8))) short bf16x8;
typedef __attribute__((ext_vector_type(4))) float f32x4;

#define WS_H_OFFSET 147456
#define WS_NEEDED (WS_H_OFFSET + (size_t)SLOT_CAP * D_MLP * 2)

__device__ inline unsigned short f32_to_bf16(float f) {
  union { float f; unsigned int u; } v; v.f = f;
  unsigned int u = v.u;
  unsigned int r = (u + 0x7FFFu + ((u >> 16) & 1u)) >> 16;  // RNE
  return (unsigned short)r;
}

__device__ inline bf16x8 pack8(float4 a, float4 b) {
  bf16x8 v;
  v[0] = (short)f32_to_bf16(a.x); v[1] = (short)f32_to_bf16(a.y);
  v[2] = (short)f32_to_bf16(a.z); v[3] = (short)f32_to_bf16(a.w);
  v[4] = (short)f32_to_bf16(b.x); v[5] = (short)f32_to_bf16(b.y);
  v[6] = (short)f32_to_bf16(b.z); v[7] = (short)f32_to_bf16(b.w);
  return v;
}

// ---------------- zero d_out ----------------
__global__ void zero_kernel(float4* __restrict__ p, int n4) {
  int i = blockIdx.x * blockDim.x + threadIdx.x;
  if (i < n4) p[i] = make_float4(0.f, 0.f, 0.f, 0.f);
}

// ---------------- gating: one wave per token ----------------
__global__ __launch_bounds__(64) void gate_kernel(const float* __restrict__ x,
                            const float* __restrict__ Wg,
                            int* __restrict__ top_idx,
                            float* __restrict__ top_w) {
  const int t = blockIdx.x;
  const int lane = threadIdx.x;  // 64 threads
  const float* xr = x + (size_t)t * D_MODEL;

  float xs[16];
#pragma unroll
  for (int i = 0; i < 16; ++i) xs[i] = xr[lane + i * 64];

  float logits[NUM_EXPERTS];
#pragma unroll
  for (int e = 0; e < NUM_EXPERTS; ++e) {
    const float* wr = Wg + (size_t)e * D_MODEL;
    float s = 0.f;
#pragma unroll
    for (int i = 0; i < 16; ++i) s += xs[i] * wr[lane + i * 64];
    for (int o = 32; o > 0; o >>= 1) s += __shfl_down(s, o);
    logits[e] = s;  // valid on lane 0
  }

  if (lane == 0) {
    int i0 = 0;
#pragma unroll
    for (int e = 1; e < NUM_EXPERTS; ++e)
      if (logits[e] > logits[i0]) i0 = e;
    int i1 = -1;
#pragma unroll
    for (int e = 0; e < NUM_EXPERTS; ++e) {
      if (e == i0) continue;
      if (i1 < 0 || logits[e] > logits[i1]) i1 = e;
    }
    // softmax over 8 then renorm top-2 == 2-way softmax over the top-2 logits
    float w0 = 1.0f / (1.0f + expf(logits[i1] - logits[i0]));
    top_idx[2 * t] = i0; top_idx[2 * t + 1] = i1;
    top_w[2 * t] = w0;   top_w[2 * t + 1] = 1.0f - w0;
  }
}

// ---------------- routing: single block ----------------
__global__ __launch_bounds__(256) void route_kernel(const int* __restrict__ top_idx,
                             const float* __restrict__ top_w,
                             int* __restrict__ hdr,
                             int* __restrict__ slot_token,
                             float* __restrict__ slot_weight) {
  __shared__ int cnt[NUM_EXPERTS];
  __shared__ int off[NUM_EXPERTS];
  __shared__ int cur[NUM_EXPERTS];
  const int tid = threadIdx.x;  // 256
  if (tid < NUM_EXPERTS) cnt[tid] = 0;
  __syncthreads();
  for (int k = tid; k < NSLOT; k += 256) atomicAdd(&cnt[top_idx[k]], 1);
  __syncthreads();
  if (tid == 0) {
    int o = 0;
    for (int e = 0; e < NUM_EXPERTS; ++e) {
      off[e] = o;
      int p = (cnt[e] + BM - 1) & ~(BM - 1);
      hdr[e] = cnt[e];      // raw count
      hdr[8 + e] = o;       // base slot offset (128-aligned)
      hdr[16 + e] = p;      // padded count
      o += p;
    }
  }
  __syncthreads();
  if (tid < NUM_EXPERTS) cur[tid] = off[tid];
  for (int i = tid; i < SLOT_CAP; i += 256) { slot_token[i] = 0; slot_weight[i] = 0.0f; }
  __syncthreads();
  for (int k = tid; k < NSLOT; k += 256) {
    int e = top_idx[k];
    int p = atomicAdd(&cur[e], 1);
    slot_token[p] = k >> 1;
    slot_weight[p] = top_w[k];
  }
}

// ---------------- GEMM1: H = silu(Xg W1^T) * (Xg W3^T), bf16 out ----------------
__global__ __launch_bounds__(256) void gemm1_kernel(const float* __restrict__ x,
                             const float* __restrict__ W1,
                             const float* __restrict__ W3,
                             const int* __restrict__ hdr,
                             const int* __restrict__ slot_token,
                             unsigned short* __restrict__ H) {
  const int e = blockIdx.z;
  const int pad_cnt = hdr[16 + e];
  const int m0 = blockIdx.y * BM;
  if (m0 >= pad_cnt) return;
  const int base = hdr[8 + e];
  const int n0 = blockIdx.x * BN;

  __shared__ unsigned short As[BM * LDT];
  __shared__ unsigned short B1s[BN * LDT];
  __shared__ unsigned short B3s[BN * LDT];

  const int tid = threadIdx.x;
  const int lane = tid & 63;
  const int wave = tid >> 6;
  const int wm = (wave >> 1) * 64;
  const int wn = (wave & 1) * 64;
  const int l15 = lane & 15;
  const int quad = lane >> 4;

  // staging: thread -> (row = tid/2, 16 cols at (tid&1)*16)
  const int sr = tid >> 1;
  const int sc = (tid & 1) * 16;
  const float* arow = x + (size_t)slot_token[base + m0 + sr] * D_MODEL + sc;
  const float* b1row = W1 + ((size_t)e * D_MLP + n0 + sr) * D_MODEL + sc;
  const float* b3row = W3 + ((size_t)e * D_MLP + n0 + sr) * D_MODEL + sc;

  const f32x4 fzero = {0.f, 0.f, 0.f, 0.f};
  f32x4 acc1[4][4], acc3[4][4];
#pragma unroll
  for (int i = 0; i < 4; ++i)
#pragma unroll
    for (int j = 0; j < 4; ++j) { acc1[i][j] = fzero; acc3[i][j] = fzero; }

  for (int k0 = 0; k0 < D_MODEL; k0 += BK) {
    const float4* ap = (const float4*)(arow + k0);
    const float4* b1p = (const float4*)(b1row + k0);
    const float4* b3p = (const float4*)(b3row + k0);
    float4 a0 = ap[0], a1 = ap[1], a2 = ap[2], a3 = ap[3];
    float4 c0 = b1p[0], c1 = b1p[1], c2 = b1p[2], c3 = b1p[3];
    float4 d0 = b3p[0], d1 = b3p[1], d2 = b3p[2], d3 = b3p[3];
    __syncthreads();
    *(bf16x8*)(&As[sr * LDT + sc]) = pack8(a0, a1);
    *(bf16x8*)(&As[sr * LDT + sc + 8]) = pack8(a2, a3);
    *(bf16x8*)(&B1s[sr * LDT + sc]) = pack8(c0, c1);
    *(bf16x8*)(&B1s[sr * LDT + sc + 8]) = pack8(c2, c3);
    *(bf16x8*)(&B3s[sr * LDT + sc]) = pack8(d0, d1);
    *(bf16x8*)(&B3s[sr * LDT + sc + 8]) = pack8(d2, d3);
    __syncthreads();

    bf16x8 a_frag[4], b1_frag[4], b3_frag[4];
#pragma unroll
    for (int i = 0; i < 4; ++i)
      a_frag[i] = *(const bf16x8*)(&As[(wm + i * 16 + l15) * LDT + quad * 8]);
#pragma unroll
    for (int j = 0; j < 4; ++j) {
      b1_frag[j] = *(const bf16x8*)(&B1s[(wn + j * 16 + l15) * LDT + quad * 8]);
      b3_frag[j] = *(const bf16x8*)(&B3s[(wn + j * 16 + l15) * LDT + quad * 8]);
    }
#pragma unroll
    for (int i = 0; i < 4; ++i)
#pragma unroll
      for (int j = 0; j < 4; ++j) {
        acc1[i][j] = __builtin_amdgcn_mfma_f32_16x16x32_bf16(a_frag[i], b1_frag[j], acc1[i][j], 0, 0, 0);
        acc3[i][j] = __builtin_amdgcn_mfma_f32_16x16x32_bf16(a_frag[i], b3_frag[j], acc3[i][j], 0, 0, 0);
      }
  }

  // epilogue: silu(h1)*h3 -> bf16 H.  D layout: col=lane&15, row=quad*4+reg
  const size_t hbase = (size_t)(base + m0);
#pragma unroll
  for (int i = 0; i < 4; ++i) {
    const int mrow = wm + i * 16 + quad * 4;
#pragma unroll
    for (int r = 0; r < 4; ++r) {
      unsigned short* hrow = H + (hbase + mrow + r) * D_MLP + n0;
#pragma unroll
      for (int j = 0; j < 4; ++j) {
        float h1 = acc1[i][j][r];
        float h3 = acc3[i][j][r];
        float s = h1 / (1.0f + __expf(-h1));
        hrow[wn + j * 16 + l15] = f32_to_bf16(s * h3);
      }
    }
  }
}

// ---------------- GEMM2: out += gate_w * (H W2^T) ----------------
__global__ __launch_bounds__(256) void gemm2_kernel(const unsigned short* __restrict__ H,
                             const float* __restrict__ W2,
                             const int* __restrict__ hdr,
                             const int* __restrict__ slot_token,
                             const float* __restrict__ slot_weight,
                             float* __restrict__ out) {
  const int e = blockIdx.z;
  const int pad_cnt = hdr[16 + e];
  const int m0 = blockIdx.y * BM;
  if (m0 >= pad_cnt) return;
  const int base = hdr[8 + e];
  const int n0 = blockIdx.x * BN;

  __shared__ unsigned short As[BM * LDT];
  __shared__ unsigned short Bs[BN * LDT];

  const int tid = threadIdx.x;
  const int lane = tid & 63;
  const int wave = tid >> 6;
  const int wm = (wave >> 1) * 64;
  const int wn = (wave & 1) * 64;
  const int l15 = lane & 15;
  const int quad = lane >> 4;

  const int sr = tid >> 1;
  const int sc = (tid & 1) * 16;
  const unsigned short* arow = H + (size_t)(base + m0 + sr) * D_MLP + sc;
  const float* brow = W2 + ((size_t)e * D_MODEL + n0 + sr) * D_MLP + sc;

  const f32x4 fzero = {0.f, 0.f, 0.f, 0.f};
  f32x4 acc[4][4];
#pragma unroll
  for (int i = 0; i < 4; ++i)
#pragma unroll
    for (int j = 0; j < 4; ++j) acc[i][j] = fzero;

  for (int k0 = 0; k0 < D_MLP; k0 += BK) {
    const uint4* ap = (const uint4*)(arow + k0);  // 8 bf16 per uint4
    uint4 a0 = ap[0], a1 = ap[1];
    const float4* bp = (const float4*)(brow + k0);
    float4 c0 = bp[0], c1 = bp[1], c2 = bp[2], c3 = bp[3];
    __syncthreads();
    *(uint4*)(&As[sr * LDT + sc]) = a0;
    *(uint4*)(&As[sr * LDT + sc + 8]) = a1;
    *(bf16x8*)(&Bs[sr * LDT + sc]) = pack8(c0, c1);
    *(bf16x8*)(&Bs[sr * LDT + sc + 8]) = pack8(c2, c3);
    __syncthreads();

    bf16x8 a_frag[4], b_frag[4];
#pragma unroll
    for (int i = 0; i < 4; ++i)
      a_frag[i] = *(const bf16x8*)(&As[(wm + i * 16 + l15) * LDT + quad * 8]);
#pragma unroll
    for (int j = 0; j < 4; ++j)
      b_frag[j] = *(const bf16x8*)(&Bs[(wn + j * 16 + l15) * LDT + quad * 8]);
#pragma unroll
    for (int i = 0; i < 4; ++i)
#pragma unroll
      for (int j = 0; j < 4; ++j)
        acc[i][j] = __builtin_amdgcn_mfma_f32_16x16x32_bf16(a_frag[i], b_frag[j], acc[i][j], 0, 0, 0);
  }

#pragma unroll
  for (int i = 0; i < 4; ++i) {
    const int mrow = wm + i * 16 + quad * 4;
#pragma unroll
    for (int r = 0; r < 4; ++r) {
      const int srow = base + m0 + mrow + r;
      const float w = slot_weight[srow];
      if (w != 0.0f) {
        const int tok = slot_token[srow];
        float* orow = out + (size_t)tok * D_MODEL + n0;
#pragma unroll
        for (int j = 0; j < 4; ++j)
          atomicAdd(&orow[wn + j * 16 + l15], acc[i][j][r] * w);
      }
    }
  }
}

extern "C" void kernel_launch(void* const* d_in, const int* in_sizes, int n_in,
                              void* d_out, int out_size, void* d_ws, size_t ws_size,
                              hipStream_t stream) {
  const float* x  = (const float*)d_in[0];
  const float* Wg = (const float*)d_in[1];
  const float* W1 = (const float*)d_in[2];
  const float* W3 = (const float*)d_in[3];
  const float* W2 = (const float*)d_in[4];
  float* out = (float*)d_out;

  // ws guard: if scratch is too small, do nothing (clean absmax failure
  // instead of an OOB write that kills the container).
  if (ws_size < WS_NEEDED) return;

  char* ws = (char*)d_ws;
  int*   top_idx     = (int*)(ws);                 // 8192 ints
  float* top_w       = (float*)(ws + 32768);       // 8192 floats
  int*   hdr         = (int*)(ws + 65536);         // 64 ints
  int*   slot_token  = (int*)(ws + 65792);         // 9216 ints
  float* slot_weight = (float*)(ws + 102656);      // 9216 floats
  unsigned short* H  = (unsigned short*)(ws + WS_H_OFFSET);  // 9216*3584 bf16 = 63 MiB

  zero_kernel<<<(out_size / 4 + 255) / 256, 256, 0, stream>>>((float4*)d_out, out_size / 4);
  gate_kernel<<<T_TOKENS, 64, 0, stream>>>(x, Wg, top_idx, top_w);
  route_kernel<<<1, 256, 0, stream>>>(top_idx, top_w, hdr, slot_token, slot_weight);
  gemm1_kernel<<<dim3(D_MLP / BN, T_TOKENS / BM, NUM_EXPERTS), 256, 0, stream>>>(
      x, W1, W3, hdr, slot_token, H);
  gemm2_kernel<<<dim3(D_MODEL / BN, T_TOKENS / BM, NUM_EXPERTS), 256, 0, stream>>>(
      H, W2, hdr, slot_token, slot_weight, out);
}